// Round 11
// baseline (435.310 us; speedup 1.0000x reference)
//
#include <hip/hip_runtime.h>
#include <hip/hip_cooperative_groups.h>
#include <hip/hip_bf16.h>

namespace cg = cooperative_groups;

// GCN: h1 = relu(Agg(x@W1)+b1); h2 = relu(Agg(h1@W2)+b2); out = meanpool(h2)@Wf+bf
// R21: cooperative mega-kernel v2. R18 failed (503us) because 256-thread
//      blocks + 36KB LDS union capped gather phases at 16 waves/CU (vs 32
//      standalone). Fix: 512-thread blocks -> 4 blocks/CU x 8 waves = 32
//      waves/CU in EVERY phase (LDS 35.9KB cap kept: 64-row GEMM tiles,
//      128-dst half-bucket ELL). 7 dispatches + memset -> 1 launch; the ~90us
//      of inter-dispatch drains (R20 accounting: 147us work vs 241us wall)
//      becomes 6 grid.sync(). Phase bodies are the R17/R20-proven ones.

constexpr int F_IN   = 128;
constexpr int HID    = 64;
constexpr int NGRAPH = 128;
constexpr int NCLS   = 2;

constexpr int EPB = 4096;    // edges per bin2 unit
constexpr int NB  = 391;     // buckets of 256 dsts
constexpr int DPB = 256;     // dsts per bucket
constexpr int ST  = 56;      // ELL stride, mult of 8

constexpr int SMEM_BYTES = 35896;  // max(bin2 35896, gemm1 34816, ell 29184, gemm2 18432, pool 2048)

typedef __attribute__((ext_vector_type(8))) short bf16x8;
typedef __attribute__((ext_vector_type(4))) float f32x4;
typedef __attribute__((ext_vector_type(4))) int   i32x4;

__device__ __forceinline__ float bf2f(unsigned short s) {
    union { unsigned u; float f; } v; v.u = ((unsigned)s) << 16; return v.f;
}
__device__ __forceinline__ unsigned short f2bf(float f) {
    union { float f; unsigned u; } v; v.f = f;
    unsigned u = v.u;
    return (unsigned short)((u + 0x7FFFu + ((u >> 16) & 1u)) >> 16);  // RNE
}
__device__ __forceinline__ void unpack8(uint4 g, float* f) {
    union { unsigned u; float x; } v;
    v.u = g.x << 16; f[0] = v.x;  v.u = g.x & 0xFFFF0000u; f[1] = v.x;
    v.u = g.y << 16; f[2] = v.x;  v.u = g.y & 0xFFFF0000u; f[3] = v.x;
    v.u = g.z << 16; f[4] = v.x;  v.u = g.z & 0xFFFF0000u; f[5] = v.x;
    v.u = g.w << 16; f[6] = v.x;  v.u = g.w & 0xFFFF0000u; f[7] = v.x;
}

// ---- gather: 64 nodes/unit (8 waves x 8 nodes); exact R13/R20 per-wave body ----
__device__ __forceinline__ void gather64(int tile,
                                         const unsigned short* __restrict__ h,
                                         const int* __restrict__ ell,
                                         const int* __restrict__ cnt,
                                         const float* __restrict__ dis,
                                         const float* __restrict__ b,
                                         unsigned short* __restrict__ outb,
                                         int N) {
    int lane = threadIdx.x & 63;
    int wv   = threadIdx.x >> 6;     // 0..7
    int nq   = lane >> 3;            // node slot 0..7
    int sl   = lane & 7;             // feature oct
    int node = tile * 64 + wv * 8 + nq;
    bool valid = node < N;
    int nc = valid ? node : N - 1;

    int deg  = cnt[nc];
    int degP = (deg + 7) & ~7;
    float dd = dis[nc];
    const uint4* h4 = (const uint4*)h;

    float acc[8], tmp[8];
    unpack8(h4[(size_t)nc * 8 + sl], acc);
    float sw = dd * dd;
    float4 bv0 = *(const float4*)&b[sl * 8];
    float4 bv1 = *(const float4*)&b[sl * 8 + 4];
    acc[0] = acc[0] * sw + bv0.x; acc[1] = acc[1] * sw + bv0.y;
    acc[2] = acc[2] * sw + bv0.z; acc[3] = acc[3] * sw + bv0.w;
    acc[4] = acc[4] * sw + bv1.x; acc[5] = acc[5] * sw + bv1.y;
    acc[6] = acc[6] * sw + bv1.z; acc[7] = acc[7] * sw + bv1.w;

    for (int j0 = 0; j0 < degP; j0 += 8) {
        int raw = ell[(size_t)nc * ST + j0 + sl];    // -1 = pad
        int   idx = (raw >= 0) ? raw : 0;
        float w   = (raw >= 0) ? dis[idx] * dd : 0.f;
#pragma unroll
        for (int jj = 0; jj < 8; ++jj) {
            int   s  = __shfl(idx, nq * 8 + jj, 64);
            float wj = __shfl(w,   nq * 8 + jj, 64);
            uint4 g = h4[(size_t)s * 8 + sl];
            unpack8(g, tmp);
#pragma unroll
            for (int q = 0; q < 8; ++q)
                acc[q] = fmaf(tmp[q], wj, acc[q]);
        }
    }
    if (valid) {
        uint4 p;
        p.x = f2bf(fmaxf(acc[0], 0.f)) | ((unsigned)f2bf(fmaxf(acc[1], 0.f)) << 16);
        p.y = f2bf(fmaxf(acc[2], 0.f)) | ((unsigned)f2bf(fmaxf(acc[3], 0.f)) << 16);
        p.z = f2bf(fmaxf(acc[4], 0.f)) | ((unsigned)f2bf(fmaxf(acc[5], 0.f)) << 16);
        p.w = f2bf(fmaxf(acc[6], 0.f)) | ((unsigned)f2bf(fmaxf(acc[7], 0.f)) << 16);
        ((uint4*)outb)[(size_t)node * 8 + sl] = p;
    }
}

__global__ __launch_bounds__(512) void k_mega(
        const float* __restrict__ x,
        const int* __restrict__ srcv, const int* __restrict__ dstv,
        const int* __restrict__ bat,
        const float* __restrict__ W1, const float* __restrict__ b1,
        const float* __restrict__ W2, const float* __restrict__ b2,
        const float* __restrict__ Wf, const float* __restrict__ bfv,
        float* __restrict__ out,
        unsigned short* __restrict__ bufA, unsigned short* __restrict__ bufB,
        int* __restrict__ ellg, int* __restrict__ cntg, float* __restrict__ disg,
        int* __restrict__ gcur, unsigned* __restrict__ bin,
        int N, int E, int cap) {
    cg::grid_group grid = cg::this_grid();
    __shared__ __align__(16) char smem[SMEM_BYTES];
    const int t  = threadIdx.x;
    const int nb = gridDim.x;
    const int nblk  = (E + EPB - 1) / EPB;   // 391
    const int gemmT = (N + 63) / 64;         // 1563 (64-row tiles)
    const int gathT = (N + 63) / 64;         // 1563 (64-node units)

    // ---- P0: zero bucket cursors ----
    for (int i = blockIdx.x * 512 + t; i < NB; i += nb * 512) gcur[i] = 0;
    grid.sync();

    // ---- P1: flattened: [0,nblk) = bin2, [nblk,nblk+gemmT) = GEMM1 ----
    for (int u = blockIdx.x; u < nblk + gemmT; u += nb) {
        __syncthreads();                       // smem reuse across units
        if (u < nblk) {
            int* h    = (int*)smem;            // NB
            int* base = h + NB;                // NB
            int* ld   = base + NB;             // EPB
            int* ls   = ld + EPB;              // EPB (total 35896 B)
            for (int i = t; i < NB; i += 512) h[i] = 0;
            __syncthreads();
            int e0 = u * EPB, e1 = min(e0 + EPB, E), n = e1 - e0;
            for (int i = t; i < n; i += 512) {
                int d = dstv[e0 + i], s = srcv[e0 + i];
                ld[i] = d; ls[i] = s;
                atomicAdd(&h[d >> 8], 1);
            }
            __syncthreads();
            for (int i = t; i < NB; i += 512) {
                int c = h[i];
                base[i] = (c > 0) ? atomicAdd(&gcur[i], c) : 0;
                h[i] = 0;                      // reuse as local cursor
            }
            __syncthreads();
            for (int i = t; i < n; i += 512) {
                int d = ld[i], s = ls[i];
                int b = d >> 8;
                int pos = base[b] + atomicAdd(&h[b], 1);
                bin[(size_t)b * cap + pos] = ((unsigned)(d & 255) << 20) | (unsigned)s;
            }
        } else {
            // GEMM1 64-row tile: bufA[64,64](bf16) = X[64,128] @ W1[128,64]
            constexpr int SRX = 136;
            unsigned short* Xs = (unsigned short*)smem;            // 17408
            unsigned short* Wt = (unsigned short*)(smem + 17408);  // 17408
            const int row0 = (u - nblk) * 64;
#pragma unroll
            for (int i = 0; i < 4; ++i) {
                int idx = i * 512 + t;         // float4 index; 32 per row
                int r = idx >> 5, c4 = idx & 31;
                int gr = row0 + r;
                float4 v = (gr < N) ? *(const float4*)&x[(size_t)gr * 128 + c4 * 4]
                                    : float4{0.f, 0.f, 0.f, 0.f};
                uint2 p{f2bf(v.x) | ((unsigned)f2bf(v.y) << 16),
                        f2bf(v.z) | ((unsigned)f2bf(v.w) << 16)};
                *(uint2*)&Xs[r * SRX + c4 * 4] = p;
            }
#pragma unroll
            for (int i = 0; i < 4; ++i) {
                int idx = i * 512 + t;         // float4 index; 16 per k-row
                int k = idx >> 4, n4 = idx & 15;
                float4 v = *(const float4*)&W1[(size_t)k * 64 + n4 * 4];
                Wt[(n4 * 4 + 0) * SRX + k] = f2bf(v.x);
                Wt[(n4 * 4 + 1) * SRX + k] = f2bf(v.y);
                Wt[(n4 * 4 + 2) * SRX + k] = f2bf(v.z);
                Wt[(n4 * 4 + 3) * SRX + k] = f2bf(v.w);
            }
            __syncthreads();
            const int ln = t & 63, wv = t >> 6;
            const int m16 = ln & 15, kg = ln >> 4;
            const int mt = wv >> 1;            // m-tile 0..3
            const int n0 = (wv & 1) * 2;       // n-tile base 0 or 2
            f32x4 c0{0.f, 0.f, 0.f, 0.f}, c1{0.f, 0.f, 0.f, 0.f};
#pragma unroll
            for (int ks = 0; ks < 4; ++ks) {
                bf16x8 a  = *(const bf16x8*)&Xs[(mt * 16 + m16) * SRX + ks * 32 + kg * 8];
                bf16x8 b0 = *(const bf16x8*)&Wt[((n0 + 0) * 16 + m16) * SRX + ks * 32 + kg * 8];
                bf16x8 b1 = *(const bf16x8*)&Wt[((n0 + 1) * 16 + m16) * SRX + ks * 32 + kg * 8];
                c0 = __builtin_amdgcn_mfma_f32_16x16x32_bf16(a, b0, c0, 0, 0, 0);
                c1 = __builtin_amdgcn_mfma_f32_16x16x32_bf16(a, b1, c1, 0, 0, 0);
            }
            __syncthreads();
            unsigned short* Cs = Xs;           // [64][64]
#pragma unroll
            for (int reg = 0; reg < 4; ++reg) {
                int r = mt * 16 + kg * 4 + reg;   // C: row=(lane>>4)*4+reg
                Cs[r * 64 + (n0 + 0) * 16 + m16] = f2bf(c0[reg]);
                Cs[r * 64 + (n0 + 1) * 16 + m16] = f2bf(c1[reg]);
            }
            __syncthreads();
            {
                int r = t >> 3, c8 = t & 7;    // 64 rows x 8 uint4
                int gr = row0 + r;
                if (gr < N)
                    *(uint4*)&bufA[(size_t)gr * 64 + c8 * 8] = *(const uint4*)&Cs[r * 64 + c8 * 8];
            }
        }
    }
    grid.sync();

    // ---- P2: ELL build, 128-dst half-buckets ----
    for (int u = blockIdx.x; u < 2 * NB; u += nb) {
        __syncthreads();
        int* lell = (int*)smem;                // 128*56*4 = 28672
        int* lcnt = (int*)(smem + 28672);      // 128*4
        const int bkt = u >> 1, half = u & 1;
        for (int i = t; i < 128; i += 512) lcnt[i] = 0;
        {
            i32x4* l4 = (i32x4*)lell;
            i32x4 m1{-1, -1, -1, -1};
            for (int i = t; i < 128 * ST / 4; i += 512) l4[i] = m1;
        }
        __syncthreads();
        int n = gcur[bkt];
        const unsigned* src = bin + (size_t)bkt * cap;
        for (int i = t; i < n; i += 512) {
            unsigned p = src[i];
            int d = (int)(p >> 20);
            if ((d >> 7) == half) {
                int dl = d & 127;
                int pos = atomicAdd(&lcnt[dl], 1);
                if (pos < ST) lell[dl * ST + pos] = (int)(p & 0xFFFFF);
            }
        }
        __syncthreads();
        int base = bkt * DPB + half * 128;
        if (base < N) {
            int lim = (N - base) * ST;
            if (lim > 128 * ST) lim = 128 * ST;
            i32x4* dst4 = (i32x4*)(ellg + (size_t)base * ST);
            const i32x4* s4 = (const i32x4*)lell;
            for (int i = t; i < (lim >> 2); i += 512) dst4[i] = s4[i];
            for (int i = t; i < 128; i += 512) {
                int r = base + i;
                if (r < N) {
                    int c = min(lcnt[i], ST);
                    cntg[r] = c;
                    disg[r] = rsqrtf((float)c + 1.0f);
                }
            }
        }
    }
    grid.sync();

    // ---- P3: gather1 (bufA -> bufB, bias b1) ----
    for (int u = blockIdx.x; u < gathT; u += nb)
        gather64(u, bufA, ellg, cntg, disg, b1, bufB, N);
    grid.sync();

    // ---- P4: GEMM2 64-row tile: bufA = bufB @ W2 ----
    for (int u = blockIdx.x; u < gemmT; u += nb) {
        __syncthreads();
        constexpr int SRX = 72;
        unsigned short* Xs = (unsigned short*)smem;           // 64*72*2=9216
        unsigned short* Wt = (unsigned short*)(smem + 9216);  // 9216
        const int row0 = u * 64;
        {
            int r = t >> 3, c8 = t & 7;        // 64 rows x 8 uint4
            int gr = row0 + r;
            uint4 v = (gr < N) ? *(const uint4*)&bufB[(size_t)gr * 64 + c8 * 8]
                               : uint4{0u, 0u, 0u, 0u};
            *(uint4*)&Xs[r * SRX + c8 * 8] = v;
        }
#pragma unroll
        for (int i = 0; i < 2; ++i) {
            int idx = i * 512 + t;             // float4 index; 16 per k-row
            int k = idx >> 4, n4 = idx & 15;
            float4 v = *(const float4*)&W2[(size_t)k * 64 + n4 * 4];
            Wt[(n4 * 4 + 0) * SRX + k] = f2bf(v.x);
            Wt[(n4 * 4 + 1) * SRX + k] = f2bf(v.y);
            Wt[(n4 * 4 + 2) * SRX + k] = f2bf(v.z);
            Wt[(n4 * 4 + 3) * SRX + k] = f2bf(v.w);
        }
        __syncthreads();
        const int ln = t & 63, wv = t >> 6;
        const int m16 = ln & 15, kg = ln >> 4;
        const int mt = wv >> 1;
        const int n0 = (wv & 1) * 2;
        f32x4 c0{0.f, 0.f, 0.f, 0.f}, c1{0.f, 0.f, 0.f, 0.f};
#pragma unroll
        for (int ks = 0; ks < 2; ++ks) {
            bf16x8 a  = *(const bf16x8*)&Xs[(mt * 16 + m16) * SRX + ks * 32 + kg * 8];
            bf16x8 b0 = *(const bf16x8*)&Wt[((n0 + 0) * 16 + m16) * SRX + ks * 32 + kg * 8];
            bf16x8 b1 = *(const bf16x8*)&Wt[((n0 + 1) * 16 + m16) * SRX + ks * 32 + kg * 8];
            c0 = __builtin_amdgcn_mfma_f32_16x16x32_bf16(a, b0, c0, 0, 0, 0);
            c1 = __builtin_amdgcn_mfma_f32_16x16x32_bf16(a, b1, c1, 0, 0, 0);
        }
        __syncthreads();
        unsigned short* Cs = Xs;
#pragma unroll
        for (int reg = 0; reg < 4; ++reg) {
            int r = mt * 16 + kg * 4 + reg;
            Cs[r * 64 + (n0 + 0) * 16 + m16] = f2bf(c0[reg]);
            Cs[r * 64 + (n0 + 1) * 16 + m16] = f2bf(c1[reg]);
        }
        __syncthreads();
        {
            int r = t >> 3, c8 = t & 7;
            int gr = row0 + r;
            if (gr < N)
                *(uint4*)&bufA[(size_t)gr * 64 + c8 * 8] = *(const uint4*)&Cs[r * 64 + c8 * 8];
        }
    }
    grid.sync();

    // ---- P5: gather2 (bufA -> bufB, bias b2) ----
    for (int u = blockIdx.x; u < gathT; u += nb)
        gather64(u, bufA, ellg, cntg, disg, b2, bufB, N);
    grid.sync();

    // ---- P6: mean-pool + head, one unit per graph (batch sorted) ----
    for (int g = blockIdx.x; g < NGRAPH; g += nb) {
        __syncthreads();
        float* part = (float*)smem;            // 8*64 floats
        int lo = 0, hi = N;
        while (lo < hi) { int mid = (lo + hi) >> 1; if (bat[mid] < g) lo = mid + 1; else hi = mid; }
        const int start = lo;
        hi = N;
        while (lo < hi) { int mid = (lo + hi) >> 1; if (bat[mid] < g + 1) lo = mid + 1; else hi = mid; }
        const int end = lo;

        const int sl = t & 7;                  // feature oct
        const int ns = t >> 3;                 // node slot 0..63
        const uint4* h4 = (const uint4*)bufB;
        float acc[8], tmp[8];
#pragma unroll
        for (int q = 0; q < 8; ++q) acc[q] = 0.f;
        for (int n = start + ns; n < end; n += 64) {
            unpack8(h4[(size_t)n * 8 + sl], tmp);
#pragma unroll
            for (int q = 0; q < 8; ++q) acc[q] += tmp[q];
        }
#pragma unroll
        for (int m = 8; m <= 32; m <<= 1)
#pragma unroll
            for (int q = 0; q < 8; ++q) acc[q] += __shfl_xor(acc[q], m, 64);
        const int lane = t & 63, w = t >> 6;
        if ((lane >> 3) == 0) {
#pragma unroll
            for (int q = 0; q < 8; ++q) part[w * 64 + sl * 8 + q] = acc[q];
        }
        __syncthreads();
        if (w == 0) {
            float tot = 0.f;
#pragma unroll
            for (int k = 0; k < 8; ++k) tot += part[k * 64 + lane];
            float invc = 1.0f / fmaxf((float)(end - start), 1.0f);
            float p = tot * invc;
            float c0 = p * Wf[lane * NCLS + 0];
            float c1 = p * Wf[lane * NCLS + 1];
#pragma unroll
            for (int m = 32; m >= 1; m >>= 1) {
                c0 += __shfl_xor(c0, m, 64);
                c1 += __shfl_xor(c1, m, 64);
            }
            if (lane == 0) {
                out[g * NCLS + 0] = c0 + bfv[0];
                out[g * NCLS + 1] = c1 + bfv[1];
            }
        }
    }
}

extern "C" void kernel_launch(void* const* d_in, const int* in_sizes, int n_in,
                              void* d_out, int out_size, void* d_ws, size_t ws_size,
                              hipStream_t stream) {
    const float* x   = (const float*)d_in[0];
    const int*   ei  = (const int*)d_in[1];
    const int*   bat = (const int*)d_in[2];
    const float* W1  = (const float*)d_in[3];
    const float* b1  = (const float*)d_in[4];
    const float* W2  = (const float*)d_in[5];
    const float* b2  = (const float*)d_in[6];
    const float* Wf  = (const float*)d_in[7];
    const float* bfv = (const float*)d_in[8];
    float* out = (float*)d_out;

    int N = in_sizes[0] / F_IN;     // 100000
    int E = in_sizes[1] / 2;        // 1600000
    const int* srcv = ei;
    const int* dstv = ei + E;
    int cap = E / NB + 1280;

    const size_t S2 = (size_t)N * HID * 2;           // 12.8 MB (bf16 buffer)
    char* ws = (char*)d_ws;
    unsigned short* bufA = (unsigned short*)ws;      // N*64 bf16
    unsigned short* bufB = (unsigned short*)(ws + S2);
    int*   ell  = (int*)(ws + 2 * S2);               // N*ST i32 (22.4 MB)
    char*  tail = ws + 2 * S2 + (size_t)N * ST * 4;
    int*   cnt  = (int*)tail;                        // N i32
    float* dis  = (float*)(tail + (size_t)N * 4);    // N f32
    int*   gcur = (int*)(tail + (size_t)N * 8);      // NB cursors/counts
    unsigned* bin = (unsigned*)(tail + (size_t)N * 8 + 4096);  // NB*cap (~8.4MB)

    // co-residency-safe grid (cached across calls)
    static int s_grid = 0;
    if (s_grid == 0) {
        int mb = 0;
        hipOccupancyMaxActiveBlocksPerMultiprocessor(&mb, k_mega, 512, 0);
        if (mb < 1) mb = 1;
        hipDeviceProp_t prop;
        int dev = 0;
        hipGetDevice(&dev);
        hipGetDeviceProperties(&prop, dev);
        int cus = prop.multiProcessorCount > 0 ? prop.multiProcessorCount : 256;
        s_grid = mb * cus;
        if (s_grid > 2048) s_grid = 2048;
    }

    void* args[] = {
        (void*)&x, (void*)&srcv, (void*)&dstv, (void*)&bat,
        (void*)&W1, (void*)&b1, (void*)&W2, (void*)&b2,
        (void*)&Wf, (void*)&bfv, (void*)&out,
        (void*)&bufA, (void*)&bufB, (void*)&ell, (void*)&cnt, (void*)&dis,
        (void*)&gcur, (void*)&bin, (void*)&N, (void*)&E, (void*)&cap
    };
    hipLaunchCooperativeKernel((const void*)k_mega, dim3(s_grid), dim3(512),
                               args, 0, stream);
}

// Round 12
// 241.414 us; speedup vs baseline: 1.8032x; 1.8032x over previous
//
#include <hip/hip_runtime.h>
#include <hip/hip_bf16.h>

// GCN: h1 = relu(Agg(x@W1)+b1); h2 = relu(Agg(h1@W2)+b2); out = meanpool(h2)@Wf+bf
// Agg = D^-1/2 (A+I) D^-1/2. fp32 wire dtypes; indices int32.
// R22: base = R20 (241.5us). Mega-kernels rejected twice (R18 503, R21 435):
//      phase-local tuning of split kernels beats boundary elimination.
//      Two soft-target fixes:
//      (1) k_pre: unit types INTERLEAVED by blockIdx (b%3==0 -> bin2, else
//          GEMM; 391:782 exact) - R17/R20 ran GEMM-first so the halves were
//          serial (45.5us ~= sum not max). Both now run from t=0.
//      (2) k_ell: 128-dst half-buckets (R18-verified body): LDS 58.3->29.2KB,
//          2->5 blocks/CU, 782 blocks, int4 init+stream-out. Costs a 2nd bin
//          read (~2us), gains 2.5x parallelism.

constexpr int F_IN   = 128;
constexpr int HID    = 64;
constexpr int NGRAPH = 128;
constexpr int NCLS   = 2;

constexpr int EPB = 4096;    // edges per bin2 unit
constexpr int NB  = 391;     // buckets of 256 dsts
constexpr int DPB = 256;     // dsts per bucket
constexpr int ST  = 56;      // ELL stride, mult of 8

typedef __attribute__((ext_vector_type(8))) short bf16x8;
typedef __attribute__((ext_vector_type(4))) float f32x4;
typedef __attribute__((ext_vector_type(4))) int   i32x4;

__device__ __forceinline__ float bf2f(unsigned short s) {
    union { unsigned u; float f; } v; v.u = ((unsigned)s) << 16; return v.f;
}
__device__ __forceinline__ unsigned short f2bf(float f) {
    union { float f; unsigned u; } v; v.f = f;
    unsigned u = v.u;
    return (unsigned short)((u + 0x7FFFu + ((u >> 16) & 1u)) >> 16);  // RNE
}
__device__ __forceinline__ void unpack8(uint4 g, float* f) {
    union { unsigned u; float x; } v;
    v.u = g.x << 16; f[0] = v.x;  v.u = g.x & 0xFFFF0000u; f[1] = v.x;
    v.u = g.y << 16; f[2] = v.x;  v.u = g.y & 0xFFFF0000u; f[3] = v.x;
    v.u = g.z << 16; f[4] = v.x;  v.u = g.z & 0xFFFF0000u; f[5] = v.x;
    v.u = g.w << 16; f[6] = v.x;  v.u = g.w & 0xFFFF0000u; f[7] = v.x;
}

// ---- fused: interleaved units. b%3==0 -> bin2 unit b/3; else GEMM1 unit. ----
__global__ __launch_bounds__(256) void k_pre(const float* __restrict__ X,
                                             const float* __restrict__ W,
                                             unsigned short* __restrict__ Y,
                                             int M,
                                             const int* __restrict__ srcv,
                                             const int* __restrict__ dstv,
                                             int* __restrict__ gcur,
                                             unsigned* __restrict__ bin,
                                             int E, int cap) {
    __shared__ __align__(16) char smem[52224];   // max(gemm 52224, bin 35896)
    const int t = threadIdx.x;
    const int b = blockIdx.x;

    if (b % 3 == 0) {
        // bin2: LDS hist (edges cached) -> claim ranges -> scatter
        int* h    = (int*)smem;            // NB
        int* base = h + NB;                // NB
        int* ld   = base + NB;             // EPB
        int* ls   = ld + EPB;              // EPB   (total 35896 B)
        const int bb = b / 3;

        for (int i = t; i < NB; i += 256) h[i] = 0;
        __syncthreads();
        int e0 = bb * EPB, e1 = min(e0 + EPB, E), n = e1 - e0;
        for (int i = t; i < n; i += 256) {
            int d = dstv[e0 + i], s = srcv[e0 + i];
            ld[i] = d; ls[i] = s;
            atomicAdd(&h[d >> 8], 1);
        }
        __syncthreads();
        for (int i = t; i < NB; i += 256) {
            int c = h[i];
            base[i] = (c > 0) ? atomicAdd(&gcur[i], c) : 0;
            h[i] = 0;                                  // reuse as local cursor
        }
        __syncthreads();
        for (int i = t; i < n; i += 256) {
            int d = ld[i], s = ls[i];
            int bk = d >> 8;
            int pos = base[bk] + atomicAdd(&h[bk], 1);
            bin[(size_t)bk * cap + pos] = ((unsigned)(d & 255) << 20) | (unsigned)s;
        }
    } else {
        constexpr int SRX = 136;   // bf16 stride (128+8)
        constexpr int SRW = 136;
        unsigned short* Xs = (unsigned short*)smem;            // 34816
        unsigned short* Wt = (unsigned short*)(smem + 34816);  // 17408
        const int gu = b - b / 3 - 1;          // gemm unit 0..781
        const int row0 = gu * 128;

#pragma unroll
        for (int i = 0; i < 16; ++i) {
            int idx = i * 256 + t;           // float4 index; 32 per row
            int r = idx >> 5, c4 = idx & 31;
            int gr = row0 + r;
            float4 v = (gr < M) ? *(const float4*)&X[(size_t)gr * 128 + c4 * 4]
                                : float4{0.f, 0.f, 0.f, 0.f};
            uint2 p{f2bf(v.x) | ((unsigned)f2bf(v.y) << 16),
                    f2bf(v.z) | ((unsigned)f2bf(v.w) << 16)};
            *(uint2*)&Xs[r * SRX + c4 * 4] = p;
        }
#pragma unroll
        for (int i = 0; i < 8; ++i) {
            int idx = i * 256 + t;           // float4 index; 16 per k-row
            int k = idx >> 4, n4 = idx & 15;
            float4 v = *(const float4*)&W[(size_t)k * 64 + n4 * 4];
            Wt[(n4 * 4 + 0) * SRW + k] = f2bf(v.x);
            Wt[(n4 * 4 + 1) * SRW + k] = f2bf(v.y);
            Wt[(n4 * 4 + 2) * SRW + k] = f2bf(v.z);
            Wt[(n4 * 4 + 3) * SRW + k] = f2bf(v.w);
        }
        __syncthreads();

        const int ln = t & 63, wv = t >> 6;
        const int m16 = ln & 15, kg = ln >> 4;
        const int rbase = wv * 32;
        f32x4 acc[2][4];
#pragma unroll
        for (int i = 0; i < 2; ++i)
#pragma unroll
            for (int j = 0; j < 4; ++j) acc[i][j] = f32x4{0.f, 0.f, 0.f, 0.f};

#pragma unroll
        for (int ks = 0; ks < 4; ++ks) {
            bf16x8 a0 = *(const bf16x8*)&Xs[(rbase + m16) * SRX + ks * 32 + kg * 8];
            bf16x8 a1 = *(const bf16x8*)&Xs[(rbase + 16 + m16) * SRX + ks * 32 + kg * 8];
#pragma unroll
            for (int ct = 0; ct < 4; ++ct) {
                bf16x8 bb = *(const bf16x8*)&Wt[(ct * 16 + m16) * SRW + ks * 32 + kg * 8];
                acc[0][ct] = __builtin_amdgcn_mfma_f32_16x16x32_bf16(a0, bb, acc[0][ct], 0, 0, 0);
                acc[1][ct] = __builtin_amdgcn_mfma_f32_16x16x32_bf16(a1, bb, acc[1][ct], 0, 0, 0);
            }
        }

        __syncthreads();                       // Xs reads done; reuse as C staging
        unsigned short* Cs = Xs;               // [128][64] bf16
#pragma unroll
        for (int mt = 0; mt < 2; ++mt)
#pragma unroll
            for (int ct = 0; ct < 4; ++ct)
#pragma unroll
                for (int reg = 0; reg < 4; ++reg) {
                    int r = rbase + mt * 16 + kg * 4 + reg;  // C: row=(lane>>4)*4+reg
                    Cs[r * 64 + ct * 16 + m16] = f2bf(acc[mt][ct][reg]);
                }
        __syncthreads();
#pragma unroll
        for (int i = 0; i < 4; ++i) {
            int idx = i * 256 + t;             // uint4 (8 bf16); 8 per row
            int r = idx >> 3, c8 = idx & 7;
            int gr = row0 + r;
            if (gr < M)
                *(uint4*)&Y[(size_t)gr * 64 + c8 * 8] = *(const uint4*)&Cs[r * 64 + c8 * 8];
        }
    }
}

// ---- build ELL in 128-dst half-buckets (R18-verified); int4 init/stream ----
__global__ __launch_bounds__(256) void k_ell(const unsigned* __restrict__ bin,
                                             const int* __restrict__ bktCnt,
                                             int* __restrict__ ellg,
                                             int* __restrict__ cntg,
                                             float* __restrict__ disg,
                                             int N, int cap) {
    __shared__ int lell[128 * ST];     // 28672 B
    __shared__ int lcnt[128];
    const int bkt = blockIdx.x >> 1, half = blockIdx.x & 1;
    const int t = threadIdx.x;
    for (int i = t; i < 128; i += 256) lcnt[i] = 0;
    {
        i32x4* l4 = (i32x4*)lell;
        i32x4 m1{-1, -1, -1, -1};
        for (int i = t; i < 128 * ST / 4; i += 256) l4[i] = m1;
    }
    __syncthreads();
    int n = bktCnt[bkt];
    const unsigned* src = bin + (size_t)bkt * cap;
    for (int i = t; i < n; i += 256) {
        unsigned p = src[i];
        int d = (int)(p >> 20);
        if ((d >> 7) == half) {
            int dl = d & 127;
            int pos = atomicAdd(&lcnt[dl], 1);
            if (pos < ST) lell[dl * ST + pos] = (int)(p & 0xFFFFF);
        }
    }
    __syncthreads();
    int base = bkt * DPB + half * 128;
    if (base >= N) return;
    int lim = (N - base) * ST;
    if (lim > 128 * ST) lim = 128 * ST;
    i32x4* dst4 = (i32x4*)(ellg + (size_t)base * ST);
    const i32x4* s4 = (const i32x4*)lell;
    for (int i = t; i < (lim >> 2); i += 256) dst4[i] = s4[i];
    for (int i = t; i < 128; i += 256) {
        int r = base + i;
        if (r < N) {
            int c = min(lcnt[i], ST);
            cntg[r] = c;
            disg[r] = rsqrtf((float)c + 1.0f);
        }
    }
}

// ---- GEMM2 (MFMA): Y[M,64](bf16) = X[M,64](bf16) @ W2[64,64](f32) ----
__global__ __launch_bounds__(256) void k_gemm_b(const unsigned short* __restrict__ X,
                                                const float* __restrict__ W,
                                                unsigned short* __restrict__ Y,
                                                int M) {
    constexpr int SRX = 72;    // bf16 stride (64+8)
    constexpr int SRW = 72;
    __shared__ unsigned short Xs[128 * SRX];   // 18.4 KB
    __shared__ unsigned short Wt[64 * SRW];    // 9.2 KB
    const int t = threadIdx.x;
    const int row0 = blockIdx.x * 128;

#pragma unroll
    for (int i = 0; i < 4; ++i) {
        int idx = i * 256 + t;             // uint4 index; 8 per row
        int r = idx >> 3, c8 = idx & 7;
        int gr = row0 + r;
        uint4 v = (gr < M) ? *(const uint4*)&X[(size_t)gr * 64 + c8 * 8]
                           : uint4{0u, 0u, 0u, 0u};
        *(uint4*)&Xs[r * SRX + c8 * 8] = v;
    }
#pragma unroll
    for (int i = 0; i < 4; ++i) {
        int idx = i * 256 + t;             // float4 index; 16 per k-row
        int k = idx >> 4, n4 = idx & 15;
        float4 v = *(const float4*)&W[(size_t)k * 64 + n4 * 4];
        Wt[(n4 * 4 + 0) * SRW + k] = f2bf(v.x);
        Wt[(n4 * 4 + 1) * SRW + k] = f2bf(v.y);
        Wt[(n4 * 4 + 2) * SRW + k] = f2bf(v.z);
        Wt[(n4 * 4 + 3) * SRW + k] = f2bf(v.w);
    }
    __syncthreads();

    const int ln = t & 63, wv = t >> 6;
    const int m16 = ln & 15, kg = ln >> 4;
    const int rbase = wv * 32;
    f32x4 acc[2][4];
#pragma unroll
    for (int i = 0; i < 2; ++i)
#pragma unroll
        for (int j = 0; j < 4; ++j) acc[i][j] = f32x4{0.f, 0.f, 0.f, 0.f};

#pragma unroll
    for (int ks = 0; ks < 2; ++ks) {
        bf16x8 a0 = *(const bf16x8*)&Xs[(rbase + m16) * SRX + ks * 32 + kg * 8];
        bf16x8 a1 = *(const bf16x8*)&Xs[(rbase + 16 + m16) * SRX + ks * 32 + kg * 8];
#pragma unroll
        for (int ct = 0; ct < 4; ++ct) {
            bf16x8 b = *(const bf16x8*)&Wt[(ct * 16 + m16) * SRW + ks * 32 + kg * 8];
            acc[0][ct] = __builtin_amdgcn_mfma_f32_16x16x32_bf16(a0, b, acc[0][ct], 0, 0, 0);
            acc[1][ct] = __builtin_amdgcn_mfma_f32_16x16x32_bf16(a1, b, acc[1][ct], 0, 0, 0);
        }
    }

    __syncthreads();
    unsigned short* Cs = Xs;
#pragma unroll
    for (int mt = 0; mt < 2; ++mt)
#pragma unroll
        for (int ct = 0; ct < 4; ++ct)
#pragma unroll
            for (int reg = 0; reg < 4; ++reg) {
                int r = rbase + mt * 16 + kg * 4 + reg;
                Cs[r * 64 + ct * 16 + m16] = f2bf(acc[mt][ct][reg]);
            }
    __syncthreads();
#pragma unroll
    for (int i = 0; i < 4; ++i) {
        int idx = i * 256 + t;
        int r = idx >> 3, c8 = idx & 7;
        int gr = row0 + r;
        if (gr < M)
            *(uint4*)&Y[(size_t)gr * 64 + c8 * 8] = *(const uint4*)&Cs[r * 64 + c8 * 8];
    }
}

// ---- gather-aggregate + self-loop + bias + relu; bf16 h, 8 nodes/wave ----
// (R13 body; L3 random-line bound ~40us — measured floor)
__global__ __launch_bounds__(256) void k_gather(const unsigned short* __restrict__ h,
                                                const int* __restrict__ ell,
                                                const int* __restrict__ cnt,
                                                const float* __restrict__ dis,
                                                const float* __restrict__ b,
                                                unsigned short* __restrict__ outb,
                                                int N) {
    int wave = (blockIdx.x * 256 + threadIdx.x) >> 6;
    int lane = threadIdx.x & 63;
    int nq   = lane >> 3;            // node slot 0..7
    int sl   = lane & 7;             // feature oct
    int node = wave * 8 + nq;
    bool valid = node < N;
    int nc = valid ? node : N - 1;

    int deg  = cnt[nc];
    int degP = (deg + 7) & ~7;
    float dd = dis[nc];
    const uint4* h4 = (const uint4*)h;

    float acc[8], tmp[8];
    unpack8(h4[(size_t)nc * 8 + sl], acc);
    float sw = dd * dd;
    float4 bv0 = *(const float4*)&b[sl * 8];
    float4 bv1 = *(const float4*)&b[sl * 8 + 4];
    acc[0] = acc[0] * sw + bv0.x; acc[1] = acc[1] * sw + bv0.y;
    acc[2] = acc[2] * sw + bv0.z; acc[3] = acc[3] * sw + bv0.w;
    acc[4] = acc[4] * sw + bv1.x; acc[5] = acc[5] * sw + bv1.y;
    acc[6] = acc[6] * sw + bv1.z; acc[7] = acc[7] * sw + bv1.w;

    for (int j0 = 0; j0 < degP; j0 += 8) {
        int raw = ell[(size_t)nc * ST + j0 + sl];    // -1 = pad
        int   idx = (raw >= 0) ? raw : 0;
        float w   = (raw >= 0) ? dis[idx] * dd : 0.f;
#pragma unroll
        for (int jj = 0; jj < 8; ++jj) {
            int   s  = __shfl(idx, nq * 8 + jj, 64);
            float wj = __shfl(w,   nq * 8 + jj, 64);
            uint4 g = h4[(size_t)s * 8 + sl];
            unpack8(g, tmp);
#pragma unroll
            for (int q = 0; q < 8; ++q)
                acc[q] = fmaf(tmp[q], wj, acc[q]);
        }
    }
    if (valid) {
        uint4 p;
        p.x = f2bf(fmaxf(acc[0], 0.f)) | ((unsigned)f2bf(fmaxf(acc[1], 0.f)) << 16);
        p.y = f2bf(fmaxf(acc[2], 0.f)) | ((unsigned)f2bf(fmaxf(acc[3], 0.f)) << 16);
        p.z = f2bf(fmaxf(acc[4], 0.f)) | ((unsigned)f2bf(fmaxf(acc[5], 0.f)) << 16);
        p.w = f2bf(fmaxf(acc[6], 0.f)) | ((unsigned)f2bf(fmaxf(acc[7], 0.f)) << 16);
        ((uint4*)outb)[(size_t)node * 8 + sl] = p;
    }
}

// ---- pool+head: one block per graph (batch sorted), no atomics ----
__global__ __launch_bounds__(256) void k_pool2(const unsigned short* __restrict__ h,
                                               const int* __restrict__ batch,
                                               const float* __restrict__ Wf,
                                               const float* __restrict__ bfv,
                                               float* __restrict__ out, int N) {
    __shared__ float part[4 * 64];
    const int g = blockIdx.x;
    const int t = threadIdx.x;

    int lo = 0, hi = N;
    while (lo < hi) { int mid = (lo + hi) >> 1; if (batch[mid] < g) lo = mid + 1; else hi = mid; }
    const int start = lo;
    hi = N;
    while (lo < hi) { int mid = (lo + hi) >> 1; if (batch[mid] < g + 1) lo = mid + 1; else hi = mid; }
    const int end = lo;

    const int sl = t & 7;            // feature oct
    const int ns = t >> 3;           // node slot 0..31
    const uint4* h4 = (const uint4*)h;
    float acc[8], tmp[8];
#pragma unroll
    for (int q = 0; q < 8; ++q) acc[q] = 0.f;
    for (int n = start + ns; n < end; n += 32) {
        unpack8(h4[(size_t)n * 8 + sl], tmp);
#pragma unroll
        for (int q = 0; q < 8; ++q) acc[q] += tmp[q];
    }
#pragma unroll
    for (int m = 8; m <= 32; m <<= 1)
#pragma unroll
        for (int q = 0; q < 8; ++q) acc[q] += __shfl_xor(acc[q], m, 64);
    const int lane = t & 63, w = t >> 6;
    if ((lane >> 3) == 0) {
#pragma unroll
        for (int q = 0; q < 8; ++q) part[w * 64 + sl * 8 + q] = acc[q];
    }
    __syncthreads();
    if (w == 0) {
        float tot = part[lane] + part[64 + lane] + part[128 + lane] + part[192 + lane];
        float invc = 1.0f / fmaxf((float)(end - start), 1.0f);
        float p = tot * invc;
        float c0 = p * Wf[lane * NCLS + 0];
        float c1 = p * Wf[lane * NCLS + 1];
#pragma unroll
        for (int m = 32; m >= 1; m >>= 1) {
            c0 += __shfl_xor(c0, m, 64);
            c1 += __shfl_xor(c1, m, 64);
        }
        if (lane == 0) {
            out[g * NCLS + 0] = c0 + bfv[0];
            out[g * NCLS + 1] = c1 + bfv[1];
        }
    }
}

extern "C" void kernel_launch(void* const* d_in, const int* in_sizes, int n_in,
                              void* d_out, int out_size, void* d_ws, size_t ws_size,
                              hipStream_t stream) {
    const float* x   = (const float*)d_in[0];
    const int*   ei  = (const int*)d_in[1];
    const int*   bat = (const int*)d_in[2];
    const float* W1  = (const float*)d_in[3];
    const float* b1  = (const float*)d_in[4];
    const float* W2  = (const float*)d_in[5];
    const float* b2  = (const float*)d_in[6];
    const float* Wf  = (const float*)d_in[7];
    const float* bfv = (const float*)d_in[8];
    float* out = (float*)d_out;

    const int N = in_sizes[0] / F_IN;     // 100000
    const int E = in_sizes[1] / 2;        // 1600000
    const int* srcv = ei;
    const int* dstv = ei + E;

    const int nblk = (E + EPB - 1) / EPB;            // 391
    const int cap  = E / NB + 1280;

    const size_t S2 = (size_t)N * HID * 2;           // 12.8 MB (bf16 buffer)
    char* ws = (char*)d_ws;
    unsigned short* bufA = (unsigned short*)ws;      // N*64 bf16
    unsigned short* bufB = (unsigned short*)(ws + S2);
    int*   ell  = (int*)(ws + 2 * S2);               // N*ST i32 (22.4 MB)
    char*  tail = ws + 2 * S2 + (size_t)N * ST * 4;
    int*   cnt  = (int*)tail;                        // N i32
    float* dis  = (float*)(tail + (size_t)N * 4);    // N f32
    int*   gcur = (int*)(tail + (size_t)N * 8);      // NB bucket cursors/counts
    unsigned* bin = (unsigned*)(tail + (size_t)N * 8 + 4096);  // NB*cap (~8.4MB)

    hipMemsetAsync(gcur, 0, (size_t)NB * 4, stream);

    // [GEMM1 interleaved with hist+scatter] -> ELL (half-buckets)
    const int gemmBlk = (N + 127) / 128;             // 782
    k_pre<<<gemmBlk + nblk, 256, 0, stream>>>(x, W1, bufA, N, srcv, dstv,
                                              gcur, bin, E, cap);
    k_ell<<<2 * NB, 256, 0, stream>>>(bin, gcur, ell, cnt, dis, N, cap);

    // layer 1 gather
    const int gathBlk = (N + 31) / 32;               // 32 nodes/block (4 waves x 8)
    k_gather<<<gathBlk, 256, 0, stream>>>(bufA, ell, cnt, dis, b1, bufB, N);

    // layer 2
    k_gemm_b<<<gemmBlk, 256, 0, stream>>>(bufB, W2, bufA, N);
    k_gather<<<gathBlk, 256, 0, stream>>>(bufA, ell, cnt, dis, b2, bufB, N);

    // mean-pool + head (one block per graph, atomic-free)
    k_pool2<<<NGRAPH, 256, 0, stream>>>(bufB, bat, Wf, bfv, out, N);
}